// Round 3
// baseline (7878.422 us; speedup 1.0000x reference)
//
#include <hip/hip_runtime.h>
#include <cstdint>

#define N_PTS 8192
#define M_PTS 4096
#define BS 4
#define CH 64
#define KNN 32
// radius*radius evaluated in Python float (f64): 0.2*0.2 = 0.04000000000000001
#define R2D (0.2 * 0.2)

// ---------------- FPS: one block per batch, f64 min-dist chain ----------------
__global__ __launch_bounds__(1024) void fps_kernel(const float* __restrict__ xyz,
                                                   float* __restrict__ child_xyz) {
  __shared__ float  sx[N_PTS], sy[N_PTS], sz[N_PTS];
  __shared__ double swv[16];
  __shared__ int    swi[16];
  __shared__ int    s_widx;

  const int b = blockIdx.x;
  const int t = threadIdx.x;
  const int lane = t & 63;
  const int wid  = t >> 6;
  const float* p = xyz + (size_t)b * N_PTS * 3;

  for (int e = t; e < N_PTS * 3; e += 1024) {
    float v = p[e];
    int i = e / 3, k = e - i * 3;
    if (k == 0) sx[i] = v; else if (k == 1) sy[i] = v; else sz[i] = v;
  }
  __syncthreads();

  // each thread owns 8 points; coords & running min_d2 in f64 registers
  double px[8], py[8], pz[8], md[8];
#pragma unroll
  for (int q = 0; q < 8; ++q) {
    int i = t + (q << 10);
    px[q] = (double)sx[i]; py[q] = (double)sy[i]; pz[q] = (double)sz[i];
    md[q] = 1e10;
  }

  int cur = 0;
  for (int it = 0; it < M_PTS; ++it) {
    const double lx = (double)sx[cur], ly = (double)sy[cur], lz = (double)sz[cur];
    if (t == 0) {
      float* o = child_xyz + ((size_t)b * M_PTS + it) * 3;
      o[0] = sx[cur]; o[1] = sy[cur]; o[2] = sz[cur];
    }
#pragma unroll
    for (int q = 0; q < 8; ++q) {
      double dx = px[q] - lx, dy = py[q] - ly, dz = pz[q] - lz;
      double d2 = dx * dx + dy * dy + dz * dz;   // products exact in f64 -> deterministic
      md[q] = fmin(md[q], d2);
    }
    // local argmax: smallest owned global index achieving the max
    double bv = md[0];
#pragma unroll
    for (int q = 1; q < 8; ++q) bv = fmax(bv, md[q]);
    int bi = t;
#pragma unroll
    for (int q = 7; q >= 0; --q) if (md[q] == bv) bi = t + (q << 10);

    // wave argmax reduce, tie -> smaller index (first-occurrence semantics)
#pragma unroll
    for (int off = 32; off; off >>= 1) {
      double ov = __shfl_xor(bv, off);
      int    oi = __shfl_xor(bi, off);
      if (ov > bv || (ov == bv && oi < bi)) { bv = ov; bi = oi; }
    }
    if (lane == 0) { swv[wid] = bv; swi[wid] = bi; }
    __syncthreads();
    if (wid == 0) {
      double rv = (lane < 16) ? swv[lane] : -1.0;
      int    ri = (lane < 16) ? swi[lane] : 0x7fffffff;
#pragma unroll
      for (int off = 8; off; off >>= 1) {
        double ov = __shfl_xor(rv, off);
        int    oi = __shfl_xor(ri, off);
        if (ov > rv || (ov == rv && oi < ri)) { rv = ov; ri = oi; }
      }
      if (lane == 0) s_widx = ri;
    }
    __syncthreads();
    cur = s_widx;
  }
}

// ---------------- feats (b,c,n) -> featsT (b,n,c) ----------------
__global__ __launch_bounds__(256) void transpose_kernel(const float* __restrict__ feats,
                                                        float* __restrict__ featsT) {
  __shared__ float tile[CH][65];
  const int b = blockIdx.y;
  const int i0 = blockIdx.x * 64;
  const int t = threadIdx.x;
  const float* src = feats + (size_t)b * CH * N_PTS;
#pragma unroll
  for (int r = 0; r < 16; ++r) {
    int e = t + r * 256;
    int c = e >> 6, ii = e & 63;
    tile[c][ii] = src[(size_t)c * N_PTS + i0 + ii];
  }
  __syncthreads();
  float* dst = featsT + ((size_t)b * N_PTS + i0) * CH;
#pragma unroll
  for (int r = 0; r < 16; ++r) {
    int e = t + r * 256;
    int ii = e >> 6, c = e & 63;
    dst[(size_t)ii * CH + c] = tile[c][ii];
  }
}

// ---------------- ball query (first-K ascending index) + feature max, fused ----------------
__global__ __launch_bounds__(1024) void ballgroup_kernel(const float* __restrict__ xyz,
                                                         const float* __restrict__ child_xyz,
                                                         const float* __restrict__ featsrc,
                                                         float* __restrict__ child_feats,
                                                         int useT) {
  __shared__ float sx[N_PTS], sy[N_PTS], sz[N_PTS];
  __shared__ int slist[16][KNN];
  const int b = blockIdx.y;
  const int t = threadIdx.x;
  const int lane = t & 63, wid = t >> 6;
  const float* p = xyz + (size_t)b * N_PTS * 3;
  for (int e = t; e < N_PTS * 3; e += 1024) {
    float v = p[e];
    int i = e / 3, k = e - i * 3;
    if (k == 0) sx[i] = v; else if (k == 1) sy[i] = v; else sz[i] = v;
  }
  __syncthreads();

  const int j = blockIdx.x * 16 + wid;           // one wave per ball
  const float* cc = child_xyz + ((size_t)b * M_PTS + j) * 3;
  const double cx = (double)cc[0], cy = (double)cc[1], cz = (double)cc[2];

  int taken = 0;
  for (int i0 = 0; i0 < N_PTS && taken < KNN; i0 += 64) {
    const int i = i0 + lane;
    double dx = cx - (double)sx[i], dy = cy - (double)sy[i], dz = cz - (double)sz[i];
    double d2 = dx * dx + dy * dy + dz * dz;
    const bool hit = d2 <= R2D;
    const unsigned long long msk = __ballot(hit);
    if (msk) {
      int slot = taken + __popcll(msk & ((1ull << lane) - 1ull));
      if (hit && slot < KNN) slist[wid][slot] = i;
      taken += (int)__popcll(msk);
    }
  }
  int cnt = taken < KNN ? taken : KNN;
  if (cnt == 0) { if (lane == 0) slist[wid][0] = 0; cnt = 1; }  // safety (self-hit guarantees >=1)

  float acc = -INFINITY;
  for (int q = 0; q < cnt; ++q) {
    const int idx = slist[wid][q];
    float v = useT ? featsrc[((size_t)b * N_PTS + idx) * CH + lane]
                   : featsrc[((size_t)b * CH + lane) * N_PTS + idx];
    acc = fmaxf(acc, v);
  }
  child_feats[((size_t)b * CH + lane) * M_PTS + j] = acc;
}

extern "C" void kernel_launch(void* const* d_in, const int* in_sizes, int n_in,
                              void* d_out, int out_size, void* d_ws, size_t ws_size,
                              hipStream_t stream) {
  const float* xyz   = (const float*)d_in[0];
  const float* feats = (const float*)d_in[1];
  float* out = (float*)d_out;
  float* child_xyz   = out;
  float* child_feats = out + (size_t)BS * M_PTS * 3;
  float* featsT = (float*)d_ws;
  const int useT = ws_size >= (size_t)BS * N_PTS * CH * sizeof(float);

  fps_kernel<<<BS, 1024, 0, stream>>>(xyz, child_xyz);
  if (useT) transpose_kernel<<<dim3(N_PTS / 64, BS), 256, 0, stream>>>(feats, featsT);
  ballgroup_kernel<<<dim3(M_PTS / 16, BS), 1024, 0, stream>>>(
      xyz, child_xyz, useT ? featsT : feats, child_feats, useT);
}